// Round 18
// baseline (70.785 us; speedup 1.0000x reference)
//
#include <hip/hip_runtime.h>

namespace {
constexpr int Bx = 8, Cc = 64, Hh = 128, Ww = 128, Co = 64;
constexpr int Ll = Hh * Ww;        // 16384 = 2^14
constexpr int NPIX = Bx * Ll;      // 131072
constexpr int TP = 32;             // pixels per block in k23
}

using short8 = __attribute__((ext_vector_type(8))) short;
using f32x4  = __attribute__((ext_vector_type(4))) float;

__device__ __forceinline__ unsigned short f32_to_bf16(float f) {
    union { float f; unsigned u; } un; un.f = f;
    unsigned r = un.u + 0x7FFFu + ((un.u >> 16) & 1u);   // round-to-nearest-even
    return (unsigned short)(r >> 16);
}
// packed pair via HW converter (RNE); no builtin on gfx950 -> inline asm
__device__ __forceinline__ unsigned cvt_pk_bf16(float lo, float hi) {
    unsigned u;
    asm("v_cvt_pk_bf16_f32 %0, %1, %2" : "=v"(u) : "v"(lo), "v"(hi));
    return u;
}
__device__ __forceinline__ float bflo(unsigned u) {
    union { unsigned x; float f; } c; c.x = u << 16; return c.f;
}
__device__ __forceinline__ float bfhi(unsigned u) {
    union { unsigned x; float f; } c; c.x = u & 0xFFFF0000u; return c.f;
}

// ---------------- k0: pack weights (8 blocks) ----------------
__global__ __launch_bounds__(256) void k0_pack_weights(
    const float* __restrict__ gate_w,   // [4][64]
    const float* __restrict__ geom_w,   // [12][64]
    const float* __restrict__ value_w,  // [64][64]
    const float* __restrict__ pw_w,     // [64][256], m = r*64+c
    float* __restrict__ wt16,           // [64][16]
    unsigned short* __restrict__ vwb16, // [4096]
    unsigned short* __restrict__ pwb16) // [64][256] bf16, m' = c*4+r
{
    const int tid0 = blockIdx.x * 256 + threadIdx.x;
    for (int idx = tid0; idx < Cc * 16; idx += 2048) {
        const int c = idx >> 4, j = idx & 15;
        wt16[idx] = (j < 4) ? gate_w[j * Cc + c] : geom_w[(j - 4) * Cc + c];
    }
    for (int flat = tid0; flat < 4096; flat += 2048) {
        const int t    = flat >> 10;
        const int ks   = (flat >> 9) & 1;
        const int lane = (flat >> 3) & 63;
        const int jj   = flat & 7;
        const int j = t * 16 + (lane & 15);
        const int c = ks * 32 + ((lane >> 4) & 3) * 8 + jj;
        vwb16[flat] = f32_to_bf16(value_w[j * Cc + c]);
    }
    for (int idx = tid0; idx < Co * 256; idx += 2048) {
        const int o = idx >> 8, m = idx & 255;
        const int r = m >> 6, c = m & 63;
        pwb16[o * 256 + c * 4 + r] = f32_to_bf16(pw_w[idx]);
    }
}

__device__ __forceinline__ float softplusf(float v) {
    return v > 20.f ? v : log1pf(__expf(v));
}

// ---------------- k1: hybrid projections, 64 px/block (grid 2048) ----------------
// (unchanged from R12/R14: planar field outputs, fp32 pixel-major v)
__global__ __launch_bounds__(256) void k1_project(
    const float* __restrict__ x,       // [B][64][L]
    const unsigned short* __restrict__ vwb16,
    const float* __restrict__ wt16,    // [64][16]
    const float* __restrict__ gate_b,  // [4]
    const float* __restrict__ geom_b,  // [12]
    float* __restrict__ v,             // [B][L][64]  (pixel-major)
    float* __restrict__ mu,            // [B][4][L]
    float* __restrict__ cs2, float* __restrict__ sn2,
    float* __restrict__ bse, float* __restrict__ hyp)  // each [B][4][L]
{
    __shared__ unsigned short xb16[64][72];   // 9,216 B
    __shared__ float part[4][64][17];         // 17,408 B; total 26.6 KB

    const int tid  = threadIdx.x;
    const int px   = tid & 63;
    const int ch   = tid >> 6;               // channel-quarter / wave id
    const int lane = tid & 63;
    const int pix0 = blockIdx.x * 64;
    const int b    = pix0 >> 14;
    const int l0   = pix0 & (Ll - 1);

    float acc[16];
#pragma unroll
    for (int j = 0; j < 16; ++j) acc[j] = 0.f;

    const float* xb = x + (size_t)b * Cc * Ll + (l0 + px);
#pragma unroll
    for (int j0 = 0; j0 < 16; j0 += 8) {
        float xv[8];
#pragma unroll
        for (int j = 0; j < 8; ++j) xv[j] = xb[(size_t)(ch * 16 + j0 + j) * Ll];
        uint4 ph;
        unsigned* hp = (unsigned*)&ph;
#pragma unroll
        for (int j = 0; j < 4; ++j)
            hp[j] = cvt_pk_bf16(xv[2 * j], xv[2 * j + 1]);
        *(uint4*)&xb16[px][ch * 16 + j0] = ph;
#pragma unroll
        for (int j = 0; j < 8; ++j) {
            const float* wr = wt16 + (ch * 16 + j0 + j) * 16;   // uniform
#pragma unroll
            for (int jj = 0; jj < 16; ++jj) acc[jj] = fmaf(wr[jj], xv[j], acc[jj]);
        }
    }
#pragma unroll
    for (int jj = 0; jj < 16; ++jj) part[ch][px][jj] = acc[jj];

    short8 af[8];
#pragma unroll
    for (int i = 0; i < 8; ++i)
        af[i] = *(const short8*)(vwb16 + ((size_t)(i * 64 + lane)) * 8);

    __syncthreads();

    {
        const int g = ch;
        const int l = l0 + px;
        const size_t fb = (size_t)b * 4 * Ll + l;
        float o[4];
#pragma unroll
        for (int q = 0; q < 4; ++q)
            o[q] = part[0][px][4 * g + q] + part[1][px][4 * g + q]
                 + part[2][px][4 * g + q] + part[3][px][4 * g + q];
        if (g == 0) {
            float e[4], gm = -1e30f;
#pragma unroll
            for (int q = 0; q < 4; ++q) { e[q] = o[q] + gate_b[q]; gm = fmaxf(gm, e[q]); }
            float gs = 0.f;
#pragma unroll
            for (int q = 0; q < 4; ++q) { e[q] = __expf(e[q] - gm); gs += e[q]; }
            const float gi = __fdividef(1.f, gs);
#pragma unroll
            for (int q = 0; q < 4; ++q) mu[fb + (size_t)q * Ll] = e[q] * gi;
        } else if (g == 1) {
#pragma unroll
            for (int q = 0; q < 4; ++q) {
                float sv, cv;
                __sincosf(2.f * (o[q] + geom_b[q]), &sv, &cv);
                cs2[fb + (size_t)q * Ll] = cv;
                sn2[fb + (size_t)q * Ll] = sv;
            }
        } else if (g == 2) {
#pragma unroll
            for (int q = 0; q < 4; ++q)
                bse[fb + (size_t)q * Ll] = softplusf(o[q] + geom_b[4 + q]) + 1e-4f;
        } else {
#pragma unroll
            for (int q = 0; q < 4; ++q)
                hyp[fb + (size_t)q * Ll] = softplusf(o[q] + geom_b[8 + q]);
        }
    }

    const int px16 = lane & 15;
    const int g2   = lane >> 4;
    {
        const int row = ch * 16 + px16;
        const short8 bh0 = *(const short8*)&xb16[row][g2 * 8];
        const short8 bh1 = *(const short8*)&xb16[row][32 + g2 * 8];

        f32x4 d0, d1, d2, d3;
#define PROJ_TILE(dst, t)                                              \
        {                                                              \
            f32x4 a_ = {0.f, 0.f, 0.f, 0.f};                           \
            a_ = __builtin_amdgcn_mfma_f32_16x16x32_bf16(af[2*(t)],   bh0, a_, 0, 0, 0); \
            a_ = __builtin_amdgcn_mfma_f32_16x16x32_bf16(af[2*(t)+1], bh1, a_, 0, 0, 0); \
            dst = a_;                                                  \
        }
        PROJ_TILE(d0, 0) PROJ_TILE(d1, 1) PROJ_TILE(d2, 2) PROJ_TILE(d3, 3)
#undef PROJ_TILE

        const int l = l0 + ch * 16 + px16;
        float* vrow = v + ((size_t)b * Ll + l) * 64 + g2 * 4;
        *(f32x4*)(vrow)      = d0;
        *(f32x4*)(vrow + 16) = d1;
        *(f32x4*)(vrow + 32) = d2;
        *(f32x4*)(vrow + 48) = d3;
    }
}

// ---------------- k23: fused compat + aggregation + MFMA pointwise ----------------
// TP=32, LDS 19968 B -> 8 blocks/CU (32 waves/CU, 2x R12's cap). Grid 4096;
// XCD-bijective swizzle gives each XCD exactly one batch image (512 tiles).
// Stage A: threads 0..127 = (px 0..31, r 0..3); waves 2-3 idle (other blocks
// fill the SIMD at 8-block residency). Stage B: wave w owns px w*8..+7,
// vv[3][10] hoisted; R12-style unpack+fma (no dot2: keeps VGPR<=64).
// Stage C: wave w -> o-tile w*16, 2 p-tiles, bias C-init.
__global__ __launch_bounds__(256, 8) void k23_fused(
    const float* __restrict__ mu,
    const float* __restrict__ cs2, const float* __restrict__ sn2,
    const float* __restrict__ bse, const float* __restrict__ hyp,
    const float* __restrict__ v,             // [B][L][64]
    const unsigned short* __restrict__ pwb16,// [64][256] bf16, m'-order
    const float* __restrict__ pw_b,          // [64]
    float* __restrict__ out)                 // [B][64][L]
{
    __shared__ unsigned wqpk[4][TP][6];      // 3,072 B
    __shared__ unsigned short agg[TP][264];  // 16,896 B

    const int tid = threadIdx.x;
    const int cpx = (int)(gridDim.x >> 3);   // 512
    const int bid = (int)((blockIdx.x & 7) * cpx + (blockIdx.x >> 3));
    const int pix0 = bid * TP;
    const int b = pix0 >> 14;
    const int l0 = pix0 & (Ll - 1);

    // ---- stage A: threads 0..127, (px, r) ----
    if (tid < 128) {
        const int px = tid & 31;
        const int r  = (tid >> 5) & 3;
        const int l  = l0 + px;
        const int hr = l >> 7;
        const int wc = l & (Ww - 1);
        const size_t fb = ((size_t)b * 4 + r) * Ll;

        const float cc = cs2[fb + l], sc = sn2[fb + l];
        const float bc = bse[fb + l], yc = hyp[fb + l];
        const float mc = mu[fb + l];

        float cmp[9];
        float sum = 0.f;
#pragma unroll
        for (int s = 0; s < 9; ++s) {
            const int dy = s / 3 - 1, dx = s % 3 - 1;
            float cv;
            if (dx == 0 && dy == 0) {
                cv = mc;
            } else {
                const int hh = hr + dy, ww = wc + dx;
                const int hcl = min(max(hh, 0), Hh - 1);
                const int wcl = min(max(ww, 0), Ww - 1);
                const bool inb = ((unsigned)hh < (unsigned)Hh) &
                                 ((unsigned)ww < (unsigned)Ww);
                const size_t ni = fb + hcl * Ww + wcl;
                const float cn = cs2[ni], sn = sn2[ni];
                const float bn = bse[ni], yn = hyp[ni];
                const float mun = inb ? mu[ni] : 0.f;
                const float c2 = cc + cn, s2 = sc + sn;
                const float h = sqrtf(fmaxf(c2 * c2 + s2 * s2, 1e-24f));
                const float rh = __fdividef(0.5f, h);
                float pu2, ps2;
                if (dx != 0 && dy != 0) {              // diagonal
                    const float t = 2.f * (float)(dx * dy) * (s2 * rh);
                    pu2 = 1.f + t; ps2 = 1.f - t;
                } else if (dx != 0) {                  // horizontal
                    pu2 = 0.5f + c2 * rh; ps2 = 0.5f - c2 * rh;
                } else {                               // vertical
                    pu2 = 0.5f - c2 * rh; ps2 = 0.5f + c2 * rh;
                }
                const float bp = 0.5f * (bc + bn);
                const float hp = 0.5f * (yc + yn);
                const float E = __expf(hp);
                const float iu = __fdividef(1.f, bp * E);   // 1/sigma_u
                const float is = E * E * iu;                // 1/sigma_s
                const float q = pu2 * (iu * iu) + ps2 * (is * is);
                cv = __expf(-q) * mun;
            }
            cmp[s] = cv;
            sum += cv;
        }
        const float inv = __fdividef(1.f, sum + 1e-6f);
        unsigned* wrow = &wqpk[r][px][0];
        wrow[0] = cvt_pk_bf16(cmp[0] * inv, cmp[1] * inv);  // s0,s1
        wrow[1] = cvt_pk_bf16(cmp[3] * inv, cmp[4] * inv);  // s3,s4
        wrow[2] = cvt_pk_bf16(cmp[6] * inv, cmp[7] * inv);  // s6,s7
        wrow[3] = cvt_pk_bf16(cmp[2] * inv, cmp[5] * inv);  // s2,s5
        wrow[4] = cvt_pk_bf16(cmp[8] * inv, 0.f);           // s8
    }
    __syncthreads();

    // ---- stage B: lane = channel, wave w owns px w*8..w*8+7 ----
    const int w = tid >> 6, c = tid & 63;
    {
        const int hr0  = l0 >> 7;
        const int rows[3] = { max(hr0 - 1, 0) * Ww, hr0 * Ww, min(hr0 + 1, Hh - 1) * Ww };
        const int colbase = (l0 & (Ww - 1)) + w * 8;
        const float* vb = v + ((size_t)b * Ll) * 64 + c;

        float vv[3][10];
#pragma unroll
        for (int ry = 0; ry < 3; ++ry)
#pragma unroll
            for (int cx = 0; cx < 10; ++cx) {
                const int col = min(max(colbase + cx - 1, 0), Ww - 1);
                vv[ry][cx] = vb[(size_t)(rows[ry] + col) * 64];
            }

#pragma unroll
        for (int p = 0; p < 8; ++p) {
            float av[4];
#pragma unroll
            for (int r = 0; r < 4; ++r) {
                const unsigned* wrow = &wqpk[r][w * 8 + p][0];
                const unsigned u0 = wrow[0], u1 = wrow[1], u2 = wrow[2],
                               u3 = wrow[3], u4 = wrow[4];
                float a;
                a = bflo(u0) * vv[0][p];                 // s0
                a = fmaf(bfhi(u0), vv[0][p + 1], a);     // s1
                a = fmaf(bflo(u3), vv[0][p + 2], a);     // s2
                a = fmaf(bflo(u1), vv[1][p],     a);     // s3
                a = fmaf(bfhi(u1), vv[1][p + 1], a);     // s4
                a = fmaf(bfhi(u3), vv[1][p + 2], a);     // s5
                a = fmaf(bflo(u2), vv[2][p],     a);     // s6
                a = fmaf(bfhi(u2), vv[2][p + 1], a);     // s7
                a = fmaf(bflo(u4), vv[2][p + 2], a);     // s8
                av[r] = a;
            }
            uint2 u;
            u.x = cvt_pk_bf16(av[0], av[1]);
            u.y = cvt_pk_bf16(av[2], av[3]);
            *((uint2*)(&agg[w * 8 + p][0]) + c) = u;    // m' = c*4+r
        }
    }

    // A fragments: issue before the barrier (in flight across it)
    const int ar    = tid & 15;
    const int chunk = (tid >> 4) & 3;
    const int o0    = w * 16;
    const unsigned short* aPtr = pwb16 + (o0 + ar) * 256 + chunk * 8;
    short8 af[8];
#pragma unroll
    for (int kt = 0; kt < 8; ++kt) af[kt] = *(const short8*)(aPtr + kt * 32);

    __syncthreads();

    // ---- stage C: MFMA pointwise, 2 p-tiles, A reused ----
    f32x4 d0, d1;
#pragma unroll
    for (int q = 0; q < 4; ++q) {
        const float bv = pw_b[o0 + chunk * 4 + q];
        d0[q] = bv; d1[q] = bv;
    }
    const unsigned short* b0 = &agg[ 0 + ar][chunk * 8];
    const unsigned short* b1 = &agg[16 + ar][chunk * 8];
#pragma unroll
    for (int kt = 0; kt < 8; ++kt) {
        d0 = __builtin_amdgcn_mfma_f32_16x16x32_bf16(af[kt], *(const short8*)(b0 + kt * 32), d0, 0, 0, 0);
        d1 = __builtin_amdgcn_mfma_f32_16x16x32_bf16(af[kt], *(const short8*)(b1 + kt * 32), d1, 0, 0, 0);
    }

#pragma unroll
    for (int q = 0; q < 4; ++q) {
        const int o = o0 + chunk * 4 + q;
        float* ob = out + ((size_t)b * Co + o) * Ll + l0 + ar;
        ob[0]  = d0[q];
        ob[16] = d1[q];
    }
}

// ---------------- launch ----------------
extern "C" void kernel_launch(void* const* d_in, const int* in_sizes, int n_in,
                              void* d_out, int out_size, void* d_ws, size_t ws_size,
                              hipStream_t stream)
{
    const float* x       = (const float*)d_in[0];
    const float* gate_w  = (const float*)d_in[1];
    const float* gate_b  = (const float*)d_in[2];
    const float* value_w = (const float*)d_in[3];
    const float* geom_w  = (const float*)d_in[4];
    const float* geom_b  = (const float*)d_in[5];
    const float* pw_w    = (const float*)d_in[6];
    const float* pw_b    = (const float*)d_in[7];
    float* out = (float*)d_out;

    float* ws  = (float*)d_ws;
    float* v    = ws;                                  // B*L*64   = 8388608
    float* mu   = v    + (size_t)Bx * Ll * 64;         // B*4*L    = 524288
    float* cs2  = mu   + (size_t)Bx * 4 * Ll;
    float* sn2  = cs2  + (size_t)Bx * 4 * Ll;
    float* bse  = sn2  + (size_t)Bx * 4 * Ll;
    float* hyp  = bse  + (size_t)Bx * 4 * Ll;
    float* wt16 = hyp  + (size_t)Bx * 4 * Ll;                 // 1024 f
    unsigned short* vwb16 = (unsigned short*)(wt16 + 1024);   // 4096 us
    unsigned short* pwb16 = vwb16 + 4096;                     // 16384 us
    // total ws: ~44 MB

    k0_pack_weights<<<8, 256, 0, stream>>>(gate_w, geom_w, value_w, pw_w,
                                           wt16, vwb16, pwb16);
    k1_project<<<NPIX / 64, 256, 0, stream>>>(x, vwb16, wt16, gate_b, geom_b,
                                              v, mu, cs2, sn2, bse, hyp);
    k23_fused<<<NPIX / TP, 256, 0, stream>>>(mu, cs2, sn2, bse, hyp,
                                             v, pwb16, pw_b, out);
}

// Round 19
// 69.229 us; speedup vs baseline: 1.0225x; 1.0225x over previous
//
#include <hip/hip_runtime.h>

namespace {
constexpr int Bx = 8, Cc = 64, Hh = 128, Ww = 128, Co = 64;
constexpr int Ll = Hh * Ww;        // 16384 = 2^14
constexpr int NPIX = Bx * Ll;      // 131072
constexpr int TP = 32;             // pixels per block in k23
}

using short8 = __attribute__((ext_vector_type(8))) short;
using f32x4  = __attribute__((ext_vector_type(4))) float;

__device__ __forceinline__ unsigned short f32_to_bf16(float f) {
    union { float f; unsigned u; } un; un.f = f;
    unsigned r = un.u + 0x7FFFu + ((un.u >> 16) & 1u);   // round-to-nearest-even
    return (unsigned short)(r >> 16);
}
// packed pair via HW converter (RNE); no builtin on gfx950 -> inline asm
__device__ __forceinline__ unsigned cvt_pk_bf16(float lo, float hi) {
    unsigned u;
    asm("v_cvt_pk_bf16_f32 %0, %1, %2" : "=v"(u) : "v"(lo), "v"(hi));
    return u;
}

// ---------------- k0: pack weights (8 blocks) ----------------
__global__ __launch_bounds__(256) void k0_pack_weights(
    const float* __restrict__ gate_w,   // [4][64]
    const float* __restrict__ geom_w,   // [12][64]
    const float* __restrict__ value_w,  // [64][64]
    const float* __restrict__ pw_w,     // [64][256], m = r*64+c
    float* __restrict__ wt16,           // [64][16]
    unsigned short* __restrict__ vwb16, // [4096]
    unsigned short* __restrict__ pwb16) // [64][256] bf16, m' = c*4+r
{
    const int tid0 = blockIdx.x * 256 + threadIdx.x;
    for (int idx = tid0; idx < Cc * 16; idx += 2048) {
        const int c = idx >> 4, j = idx & 15;
        wt16[idx] = (j < 4) ? gate_w[j * Cc + c] : geom_w[(j - 4) * Cc + c];
    }
    for (int flat = tid0; flat < 4096; flat += 2048) {
        const int t    = flat >> 10;
        const int ks   = (flat >> 9) & 1;
        const int lane = (flat >> 3) & 63;
        const int jj   = flat & 7;
        const int j = t * 16 + (lane & 15);
        const int c = ks * 32 + ((lane >> 4) & 3) * 8 + jj;
        vwb16[flat] = f32_to_bf16(value_w[j * Cc + c]);
    }
    for (int idx = tid0; idx < Co * 256; idx += 2048) {
        const int o = idx >> 8, m = idx & 255;
        const int r = m >> 6, c = m & 63;
        pwb16[o * 256 + c * 4 + r] = f32_to_bf16(pw_w[idx]);
    }
}

__device__ __forceinline__ float softplusf(float v) {
    return v > 20.f ? v : log1pf(__expf(v));
}

// ---------------- k1: hybrid projections, 64 px/block (grid 2048) ----------------
// (unchanged from R12/R14: planar field outputs, fp32 pixel-major v)
__global__ __launch_bounds__(256) void k1_project(
    const float* __restrict__ x,       // [B][64][L]
    const unsigned short* __restrict__ vwb16,
    const float* __restrict__ wt16,    // [64][16]
    const float* __restrict__ gate_b,  // [4]
    const float* __restrict__ geom_b,  // [12]
    float* __restrict__ v,             // [B][L][64]  (pixel-major)
    float* __restrict__ mu,            // [B][4][L]
    float* __restrict__ cs2, float* __restrict__ sn2,
    float* __restrict__ bse, float* __restrict__ hyp)  // each [B][4][L]
{
    __shared__ unsigned short xb16[64][72];   // 9,216 B
    __shared__ float part[4][64][17];         // 17,408 B; total 26.6 KB

    const int tid  = threadIdx.x;
    const int px   = tid & 63;
    const int ch   = tid >> 6;               // channel-quarter / wave id
    const int lane = tid & 63;
    const int pix0 = blockIdx.x * 64;
    const int b    = pix0 >> 14;
    const int l0   = pix0 & (Ll - 1);

    float acc[16];
#pragma unroll
    for (int j = 0; j < 16; ++j) acc[j] = 0.f;

    const float* xb = x + (size_t)b * Cc * Ll + (l0 + px);
#pragma unroll
    for (int j0 = 0; j0 < 16; j0 += 8) {
        float xv[8];
#pragma unroll
        for (int j = 0; j < 8; ++j) xv[j] = xb[(size_t)(ch * 16 + j0 + j) * Ll];
        uint4 ph;
        unsigned* hp = (unsigned*)&ph;
#pragma unroll
        for (int j = 0; j < 4; ++j)
            hp[j] = cvt_pk_bf16(xv[2 * j], xv[2 * j + 1]);
        *(uint4*)&xb16[px][ch * 16 + j0] = ph;
#pragma unroll
        for (int j = 0; j < 8; ++j) {
            const float* wr = wt16 + (ch * 16 + j0 + j) * 16;   // uniform
#pragma unroll
            for (int jj = 0; jj < 16; ++jj) acc[jj] = fmaf(wr[jj], xv[j], acc[jj]);
        }
    }
#pragma unroll
    for (int jj = 0; jj < 16; ++jj) part[ch][px][jj] = acc[jj];

    short8 af[8];
#pragma unroll
    for (int i = 0; i < 8; ++i)
        af[i] = *(const short8*)(vwb16 + ((size_t)(i * 64 + lane)) * 8);

    __syncthreads();

    {
        const int g = ch;
        const int l = l0 + px;
        const size_t fb = (size_t)b * 4 * Ll + l;
        float o[4];
#pragma unroll
        for (int q = 0; q < 4; ++q)
            o[q] = part[0][px][4 * g + q] + part[1][px][4 * g + q]
                 + part[2][px][4 * g + q] + part[3][px][4 * g + q];
        if (g == 0) {
            float e[4], gm = -1e30f;
#pragma unroll
            for (int q = 0; q < 4; ++q) { e[q] = o[q] + gate_b[q]; gm = fmaxf(gm, e[q]); }
            float gs = 0.f;
#pragma unroll
            for (int q = 0; q < 4; ++q) { e[q] = __expf(e[q] - gm); gs += e[q]; }
            const float gi = __fdividef(1.f, gs);
#pragma unroll
            for (int q = 0; q < 4; ++q) mu[fb + (size_t)q * Ll] = e[q] * gi;
        } else if (g == 1) {
#pragma unroll
            for (int q = 0; q < 4; ++q) {
                float sv, cv;
                __sincosf(2.f * (o[q] + geom_b[q]), &sv, &cv);
                cs2[fb + (size_t)q * Ll] = cv;
                sn2[fb + (size_t)q * Ll] = sv;
            }
        } else if (g == 2) {
#pragma unroll
            for (int q = 0; q < 4; ++q)
                bse[fb + (size_t)q * Ll] = softplusf(o[q] + geom_b[4 + q]) + 1e-4f;
        } else {
#pragma unroll
            for (int q = 0; q < 4; ++q)
                hyp[fb + (size_t)q * Ll] = softplusf(o[q] + geom_b[8 + q]);
        }
    }

    const int px16 = lane & 15;
    const int g2   = lane >> 4;
    {
        const int row = ch * 16 + px16;
        const short8 bh0 = *(const short8*)&xb16[row][g2 * 8];
        const short8 bh1 = *(const short8*)&xb16[row][32 + g2 * 8];

        f32x4 d0, d1, d2, d3;
#define PROJ_TILE(dst, t)                                              \
        {                                                              \
            f32x4 a_ = {0.f, 0.f, 0.f, 0.f};                           \
            a_ = __builtin_amdgcn_mfma_f32_16x16x32_bf16(af[2*(t)],   bh0, a_, 0, 0, 0); \
            a_ = __builtin_amdgcn_mfma_f32_16x16x32_bf16(af[2*(t)+1], bh1, a_, 0, 0, 0); \
            dst = a_;                                                  \
        }
        PROJ_TILE(d0, 0) PROJ_TILE(d1, 1) PROJ_TILE(d2, 2) PROJ_TILE(d3, 3)
#undef PROJ_TILE

        const int l = l0 + ch * 16 + px16;
        float* vrow = v + ((size_t)b * Ll + l) * 64 + g2 * 4;
        *(f32x4*)(vrow)      = d0;
        *(f32x4*)(vrow + 16) = d1;
        *(f32x4*)(vrow + 32) = d2;
        *(f32x4*)(vrow + 48) = d3;
    }
}

// ---------------- k23: fused compat + aggregation + MFMA pointwise ----------------
// TP=32; wq stored FP32 in LDS (no per-use unpack — R18's bf16 packing saved
// LDS but its 9 unpacks + 5 scalar LDS reads per (px,r) ate the occupancy
// gain; kernel is VALU-ISSUE-bound per R18 counters: occupancy 28->60 with
// flat duration). LDS 23552 B -> 6 blocks/CU (24 waves). XCD swizzle kept.
// Stage A: threads 0..127 = (px, r), fp32 writes wqlds[px][r*12+s].
// Stage B: wave w owns px w*8..+7; per (px,r): 2x ds_read_b128 + 1 scalar +
// 9 fma (zero unpacks); agg packed bf16 via 2 cvt_pk.
// Stage C: wave w -> o-tile w*16, 2 p-tiles, bias C-init.
__global__ __launch_bounds__(256, 6) void k23_fused(
    const float* __restrict__ mu,
    const float* __restrict__ cs2, const float* __restrict__ sn2,
    const float* __restrict__ bse, const float* __restrict__ hyp,
    const float* __restrict__ v,             // [B][L][64]
    const unsigned short* __restrict__ pwb16,// [64][256] bf16, m'-order
    const float* __restrict__ pw_b,          // [64]
    float* __restrict__ out)                 // [B][64][L]
{
    __shared__ float wqlds[TP * 52];         // 6,656 B  [px][r*12+s]
    __shared__ unsigned short agg[TP][264];  // 16,896 B

    const int tid = threadIdx.x;
    const int cpx = (int)(gridDim.x >> 3);   // 512
    const int bid = (int)((blockIdx.x & 7) * cpx + (blockIdx.x >> 3));
    const int pix0 = bid * TP;
    const int b = pix0 >> 14;
    const int l0 = pix0 & (Ll - 1);

    // ---- stage A: threads 0..127, (px, r) ----
    if (tid < 128) {
        const int px = tid & 31;
        const int r  = (tid >> 5) & 3;
        const int l  = l0 + px;
        const int hr = l >> 7;
        const int wc = l & (Ww - 1);
        const size_t fb = ((size_t)b * 4 + r) * Ll;

        const float cc = cs2[fb + l], sc = sn2[fb + l];
        const float bc = bse[fb + l], yc = hyp[fb + l];
        const float mc = mu[fb + l];

        float cmp[9];
        float sum = 0.f;
#pragma unroll
        for (int s = 0; s < 9; ++s) {
            const int dy = s / 3 - 1, dx = s % 3 - 1;
            float cv;
            if (dx == 0 && dy == 0) {
                cv = mc;
            } else {
                const int hh = hr + dy, ww = wc + dx;
                const int hcl = min(max(hh, 0), Hh - 1);
                const int wcl = min(max(ww, 0), Ww - 1);
                const bool inb = ((unsigned)hh < (unsigned)Hh) &
                                 ((unsigned)ww < (unsigned)Ww);
                const size_t ni = fb + hcl * Ww + wcl;
                const float cn = cs2[ni], sn = sn2[ni];
                const float bn = bse[ni], yn = hyp[ni];
                const float mun = inb ? mu[ni] : 0.f;
                const float c2 = cc + cn, s2 = sc + sn;
                const float h = sqrtf(fmaxf(c2 * c2 + s2 * s2, 1e-24f));
                const float rh = __fdividef(0.5f, h);
                float pu2, ps2;
                if (dx != 0 && dy != 0) {              // diagonal
                    const float t = 2.f * (float)(dx * dy) * (s2 * rh);
                    pu2 = 1.f + t; ps2 = 1.f - t;
                } else if (dx != 0) {                  // horizontal
                    pu2 = 0.5f + c2 * rh; ps2 = 0.5f - c2 * rh;
                } else {                               // vertical
                    pu2 = 0.5f - c2 * rh; ps2 = 0.5f + c2 * rh;
                }
                const float bp = 0.5f * (bc + bn);
                const float hp = 0.5f * (yc + yn);
                const float E = __expf(hp);
                const float iu = __fdividef(1.f, bp * E);   // 1/sigma_u
                const float is = E * E * iu;                // 1/sigma_s
                const float q = pu2 * (iu * iu) + ps2 * (is * is);
                cv = __expf(-q) * mun;
            }
            cmp[s] = cv;
            sum += cv;
        }
        const float inv = __fdividef(1.f, sum + 1e-6f);
        float* wrow = &wqlds[px * 52 + r * 12];
#pragma unroll
        for (int s = 0; s < 9; ++s) wrow[s] = cmp[s] * inv;
    }
    __syncthreads();

    // ---- stage B: lane = channel, wave w owns px w*8..w*8+7 ----
    const int w = tid >> 6, c = tid & 63;
    {
        const int hr0  = l0 >> 7;
        const int rows[3] = { max(hr0 - 1, 0) * Ww, hr0 * Ww, min(hr0 + 1, Hh - 1) * Ww };
        const int colbase = (l0 & (Ww - 1)) + w * 8;
        const float* vb = v + ((size_t)b * Ll) * 64 + c;

        float vv[3][10];
#pragma unroll
        for (int ry = 0; ry < 3; ++ry)
#pragma unroll
            for (int cx = 0; cx < 10; ++cx) {
                const int col = min(max(colbase + cx - 1, 0), Ww - 1);
                vv[ry][cx] = vb[(size_t)(rows[ry] + col) * 64];
            }

#pragma unroll
        for (int p = 0; p < 8; ++p) {
            const float* wrow = &wqlds[(w * 8 + p) * 52];
            float av[4];
#pragma unroll
            for (int r = 0; r < 4; ++r) {
                const float4 w0 = *(const float4*)(wrow + r * 12);      // s0..3
                const float4 w1 = *(const float4*)(wrow + r * 12 + 4);  // s4..7
                const float  w8 = wrow[r * 12 + 8];
                float a;
                a = w0.x * vv[0][p];
                a = fmaf(w0.y, vv[0][p + 1], a);
                a = fmaf(w0.z, vv[0][p + 2], a);
                a = fmaf(w0.w, vv[1][p],     a);
                a = fmaf(w1.x, vv[1][p + 1], a);
                a = fmaf(w1.y, vv[1][p + 2], a);
                a = fmaf(w1.z, vv[2][p],     a);
                a = fmaf(w1.w, vv[2][p + 1], a);
                a = fmaf(w8,   vv[2][p + 2], a);
                av[r] = a;
            }
            uint2 u;
            u.x = cvt_pk_bf16(av[0], av[1]);
            u.y = cvt_pk_bf16(av[2], av[3]);
            *((uint2*)(&agg[w * 8 + p][0]) + c) = u;    // m' = c*4+r
        }
    }

    // A fragments: issue before the barrier (in flight across it)
    const int ar    = tid & 15;
    const int chunk = (tid >> 4) & 3;
    const int o0    = w * 16;
    const unsigned short* aPtr = pwb16 + (o0 + ar) * 256 + chunk * 8;
    short8 af[8];
#pragma unroll
    for (int kt = 0; kt < 8; ++kt) af[kt] = *(const short8*)(aPtr + kt * 32);

    __syncthreads();

    // ---- stage C: MFMA pointwise, 2 p-tiles, A reused ----
    f32x4 d0, d1;
#pragma unroll
    for (int q = 0; q < 4; ++q) {
        const float bv = pw_b[o0 + chunk * 4 + q];
        d0[q] = bv; d1[q] = bv;
    }
    const unsigned short* b0 = &agg[ 0 + ar][chunk * 8];
    const unsigned short* b1 = &agg[16 + ar][chunk * 8];
#pragma unroll
    for (int kt = 0; kt < 8; ++kt) {
        d0 = __builtin_amdgcn_mfma_f32_16x16x32_bf16(af[kt], *(const short8*)(b0 + kt * 32), d0, 0, 0, 0);
        d1 = __builtin_amdgcn_mfma_f32_16x16x32_bf16(af[kt], *(const short8*)(b1 + kt * 32), d1, 0, 0, 0);
    }

#pragma unroll
    for (int q = 0; q < 4; ++q) {
        const int o = o0 + chunk * 4 + q;
        float* ob = out + ((size_t)b * Co + o) * Ll + l0 + ar;
        ob[0]  = d0[q];
        ob[16] = d1[q];
    }
}

// ---------------- launch ----------------
extern "C" void kernel_launch(void* const* d_in, const int* in_sizes, int n_in,
                              void* d_out, int out_size, void* d_ws, size_t ws_size,
                              hipStream_t stream)
{
    const float* x       = (const float*)d_in[0];
    const float* gate_w  = (const float*)d_in[1];
    const float* gate_b  = (const float*)d_in[2];
    const float* value_w = (const float*)d_in[3];
    const float* geom_w  = (const float*)d_in[4];
    const float* geom_b  = (const float*)d_in[5];
    const float* pw_w    = (const float*)d_in[6];
    const float* pw_b    = (const float*)d_in[7];
    float* out = (float*)d_out;

    float* ws  = (float*)d_ws;
    float* v    = ws;                                  // B*L*64   = 8388608
    float* mu   = v    + (size_t)Bx * Ll * 64;         // B*4*L    = 524288
    float* cs2  = mu   + (size_t)Bx * 4 * Ll;
    float* sn2  = cs2  + (size_t)Bx * 4 * Ll;
    float* bse  = sn2  + (size_t)Bx * 4 * Ll;
    float* hyp  = bse  + (size_t)Bx * 4 * Ll;
    float* wt16 = hyp  + (size_t)Bx * 4 * Ll;                 // 1024 f
    unsigned short* vwb16 = (unsigned short*)(wt16 + 1024);   // 4096 us
    unsigned short* pwb16 = vwb16 + 4096;                     // 16384 us
    // total ws: ~44 MB

    k0_pack_weights<<<8, 256, 0, stream>>>(gate_w, geom_w, value_w, pw_w,
                                           wt16, vwb16, pwb16);
    k1_project<<<NPIX / 64, 256, 0, stream>>>(x, vwb16, wt16, gate_b, geom_b,
                                              v, mu, cs2, sn2, bse, hyp);
    k23_fused<<<NPIX / TP, 256, 0, stream>>>(mu, cs2, sn2, bse, hyp,
                                             v, pwb16, pw_b, out);
}

// Round 20
// 69.098 us; speedup vs baseline: 1.0244x; 1.0019x over previous
//
#include <hip/hip_runtime.h>

namespace {
constexpr int Bx = 8, Cc = 64, Hh = 128, Ww = 128, Co = 64;
constexpr int Ll = Hh * Ww;        // 16384 = 2^14
constexpr int NPIX = Bx * Ll;      // 131072
constexpr int TP = 32;             // pixels per block in k23
}

using short8 = __attribute__((ext_vector_type(8))) short;
using f32x4  = __attribute__((ext_vector_type(4))) float;

__device__ __forceinline__ unsigned short f32_to_bf16(float f) {
    union { float f; unsigned u; } un; un.f = f;
    unsigned r = un.u + 0x7FFFu + ((un.u >> 16) & 1u);   // round-to-nearest-even
    return (unsigned short)(r >> 16);
}
// packed pair via HW converter (RNE); no builtin on gfx950 -> inline asm
__device__ __forceinline__ unsigned cvt_pk_bf16(float lo, float hi) {
    unsigned u;
    asm("v_cvt_pk_bf16_f32 %0, %1, %2" : "=v"(u) : "v"(lo), "v"(hi));
    return u;
}

// ---------------- k0: pack weights (8 blocks) ----------------
__global__ __launch_bounds__(256) void k0_pack_weights(
    const float* __restrict__ gate_w,   // [4][64]
    const float* __restrict__ geom_w,   // [12][64]
    const float* __restrict__ value_w,  // [64][64]
    const float* __restrict__ pw_w,     // [64][256], m = r*64+c
    float* __restrict__ wt16,           // [64][16]
    unsigned short* __restrict__ vwb16, // [4096]
    unsigned short* __restrict__ pwb16) // [64][256] bf16, m' = c*4+r
{
    const int tid0 = blockIdx.x * 256 + threadIdx.x;
    for (int idx = tid0; idx < Cc * 16; idx += 2048) {
        const int c = idx >> 4, j = idx & 15;
        wt16[idx] = (j < 4) ? gate_w[j * Cc + c] : geom_w[(j - 4) * Cc + c];
    }
    for (int flat = tid0; flat < 4096; flat += 2048) {
        const int t    = flat >> 10;
        const int ks   = (flat >> 9) & 1;
        const int lane = (flat >> 3) & 63;
        const int jj   = flat & 7;
        const int j = t * 16 + (lane & 15);
        const int c = ks * 32 + ((lane >> 4) & 3) * 8 + jj;
        vwb16[flat] = f32_to_bf16(value_w[j * Cc + c]);
    }
    for (int idx = tid0; idx < Co * 256; idx += 2048) {
        const int o = idx >> 8, m = idx & 255;
        const int r = m >> 6, c = m & 63;
        pwb16[o * 256 + c * 4 + r] = f32_to_bf16(pw_w[idx]);
    }
}

__device__ __forceinline__ float softplusf(float v) {
    return v > 20.f ? v : log1pf(__expf(v));
}

// ---------------- k1: hybrid projections, 64 px/block (grid 2048) ----------------
// (unchanged from R12/R14: planar field outputs, fp32 pixel-major v)
__global__ __launch_bounds__(256) void k1_project(
    const float* __restrict__ x,       // [B][64][L]
    const unsigned short* __restrict__ vwb16,
    const float* __restrict__ wt16,    // [64][16]
    const float* __restrict__ gate_b,  // [4]
    const float* __restrict__ geom_b,  // [12]
    float* __restrict__ v,             // [B][L][64]  (pixel-major)
    float* __restrict__ mu,            // [B][4][L]
    float* __restrict__ cs2, float* __restrict__ sn2,
    float* __restrict__ bse, float* __restrict__ hyp)  // each [B][4][L]
{
    __shared__ unsigned short xb16[64][72];   // 9,216 B
    __shared__ float part[4][64][17];         // 17,408 B; total 26.6 KB

    const int tid  = threadIdx.x;
    const int px   = tid & 63;
    const int ch   = tid >> 6;               // channel-quarter / wave id
    const int lane = tid & 63;
    const int pix0 = blockIdx.x * 64;
    const int b    = pix0 >> 14;
    const int l0   = pix0 & (Ll - 1);

    float acc[16];
#pragma unroll
    for (int j = 0; j < 16; ++j) acc[j] = 0.f;

    const float* xb = x + (size_t)b * Cc * Ll + (l0 + px);
#pragma unroll
    for (int j0 = 0; j0 < 16; j0 += 8) {
        float xv[8];
#pragma unroll
        for (int j = 0; j < 8; ++j) xv[j] = xb[(size_t)(ch * 16 + j0 + j) * Ll];
        uint4 ph;
        unsigned* hp = (unsigned*)&ph;
#pragma unroll
        for (int j = 0; j < 4; ++j)
            hp[j] = cvt_pk_bf16(xv[2 * j], xv[2 * j + 1]);
        *(uint4*)&xb16[px][ch * 16 + j0] = ph;
#pragma unroll
        for (int j = 0; j < 8; ++j) {
            const float* wr = wt16 + (ch * 16 + j0 + j) * 16;   // uniform
#pragma unroll
            for (int jj = 0; jj < 16; ++jj) acc[jj] = fmaf(wr[jj], xv[j], acc[jj]);
        }
    }
#pragma unroll
    for (int jj = 0; jj < 16; ++jj) part[ch][px][jj] = acc[jj];

    short8 af[8];
#pragma unroll
    for (int i = 0; i < 8; ++i)
        af[i] = *(const short8*)(vwb16 + ((size_t)(i * 64 + lane)) * 8);

    __syncthreads();

    {
        const int g = ch;
        const int l = l0 + px;
        const size_t fb = (size_t)b * 4 * Ll + l;
        float o[4];
#pragma unroll
        for (int q = 0; q < 4; ++q)
            o[q] = part[0][px][4 * g + q] + part[1][px][4 * g + q]
                 + part[2][px][4 * g + q] + part[3][px][4 * g + q];
        if (g == 0) {
            float e[4], gm = -1e30f;
#pragma unroll
            for (int q = 0; q < 4; ++q) { e[q] = o[q] + gate_b[q]; gm = fmaxf(gm, e[q]); }
            float gs = 0.f;
#pragma unroll
            for (int q = 0; q < 4; ++q) { e[q] = __expf(e[q] - gm); gs += e[q]; }
            const float gi = __fdividef(1.f, gs);
#pragma unroll
            for (int q = 0; q < 4; ++q) mu[fb + (size_t)q * Ll] = e[q] * gi;
        } else if (g == 1) {
#pragma unroll
            for (int q = 0; q < 4; ++q) {
                float sv, cv;
                __sincosf(2.f * (o[q] + geom_b[q]), &sv, &cv);
                cs2[fb + (size_t)q * Ll] = cv;
                sn2[fb + (size_t)q * Ll] = sv;
            }
        } else if (g == 2) {
#pragma unroll
            for (int q = 0; q < 4; ++q)
                bse[fb + (size_t)q * Ll] = softplusf(o[q] + geom_b[4 + q]) + 1e-4f;
        } else {
#pragma unroll
            for (int q = 0; q < 4; ++q)
                hyp[fb + (size_t)q * Ll] = softplusf(o[q] + geom_b[8 + q]);
        }
    }

    const int px16 = lane & 15;
    const int g2   = lane >> 4;
    {
        const int row = ch * 16 + px16;
        const short8 bh0 = *(const short8*)&xb16[row][g2 * 8];
        const short8 bh1 = *(const short8*)&xb16[row][32 + g2 * 8];

        f32x4 d0, d1, d2, d3;
#define PROJ_TILE(dst, t)                                              \
        {                                                              \
            f32x4 a_ = {0.f, 0.f, 0.f, 0.f};                           \
            a_ = __builtin_amdgcn_mfma_f32_16x16x32_bf16(af[2*(t)],   bh0, a_, 0, 0, 0); \
            a_ = __builtin_amdgcn_mfma_f32_16x16x32_bf16(af[2*(t)+1], bh1, a_, 0, 0, 0); \
            dst = a_;                                                  \
        }
        PROJ_TILE(d0, 0) PROJ_TILE(d1, 1) PROJ_TILE(d2, 2) PROJ_TILE(d3, 3)
#undef PROJ_TILE

        const int l = l0 + ch * 16 + px16;
        float* vrow = v + ((size_t)b * Ll + l) * 64 + g2 * 4;
        *(f32x4*)(vrow)      = d0;
        *(f32x4*)(vrow + 16) = d1;
        *(f32x4*)(vrow + 32) = d2;
        *(f32x4*)(vrow + 48) = d3;
    }
}

// ---------------- k23: fused compat + aggregation + MFMA pointwise ----------------
// TP=32; wq stored FP32 in LDS (no per-use unpack — R18's bf16 packing saved
// LDS but its 9 unpacks + 5 scalar LDS reads per (px,r) ate the occupancy
// gain; kernel is VALU-ISSUE-bound per R18 counters: occupancy 28->60 with
// flat duration). LDS 23552 B -> 6 blocks/CU (24 waves). XCD swizzle kept.
// Stage A: threads 0..127 = (px, r), fp32 writes wqlds[px][r*12+s].
// Stage B: wave w owns px w*8..+7; per (px,r): 2x ds_read_b128 + 1 scalar +
// 9 fma (zero unpacks); agg packed bf16 via 2 cvt_pk.
// Stage C: wave w -> o-tile w*16, 2 p-tiles, bias C-init.
__global__ __launch_bounds__(256, 6) void k23_fused(
    const float* __restrict__ mu,
    const float* __restrict__ cs2, const float* __restrict__ sn2,
    const float* __restrict__ bse, const float* __restrict__ hyp,
    const float* __restrict__ v,             // [B][L][64]
    const unsigned short* __restrict__ pwb16,// [64][256] bf16, m'-order
    const float* __restrict__ pw_b,          // [64]
    float* __restrict__ out)                 // [B][64][L]
{
    __shared__ float wqlds[TP * 52];         // 6,656 B  [px][r*12+s]
    __shared__ unsigned short agg[TP][264];  // 16,896 B

    const int tid = threadIdx.x;
    const int cpx = (int)(gridDim.x >> 3);   // 512
    const int bid = (int)((blockIdx.x & 7) * cpx + (blockIdx.x >> 3));
    const int pix0 = bid * TP;
    const int b = pix0 >> 14;
    const int l0 = pix0 & (Ll - 1);

    // ---- stage A: threads 0..127, (px, r) ----
    if (tid < 128) {
        const int px = tid & 31;
        const int r  = (tid >> 5) & 3;
        const int l  = l0 + px;
        const int hr = l >> 7;
        const int wc = l & (Ww - 1);
        const size_t fb = ((size_t)b * 4 + r) * Ll;

        const float cc = cs2[fb + l], sc = sn2[fb + l];
        const float bc = bse[fb + l], yc = hyp[fb + l];
        const float mc = mu[fb + l];

        float cmp[9];
        float sum = 0.f;
#pragma unroll
        for (int s = 0; s < 9; ++s) {
            const int dy = s / 3 - 1, dx = s % 3 - 1;
            float cv;
            if (dx == 0 && dy == 0) {
                cv = mc;
            } else {
                const int hh = hr + dy, ww = wc + dx;
                const int hcl = min(max(hh, 0), Hh - 1);
                const int wcl = min(max(ww, 0), Ww - 1);
                const bool inb = ((unsigned)hh < (unsigned)Hh) &
                                 ((unsigned)ww < (unsigned)Ww);
                const size_t ni = fb + hcl * Ww + wcl;
                const float cn = cs2[ni], sn = sn2[ni];
                const float bn = bse[ni], yn = hyp[ni];
                const float mun = inb ? mu[ni] : 0.f;
                const float c2 = cc + cn, s2 = sc + sn;
                const float h = sqrtf(fmaxf(c2 * c2 + s2 * s2, 1e-24f));
                const float rh = __fdividef(0.5f, h);
                float pu2, ps2;
                if (dx != 0 && dy != 0) {              // diagonal
                    const float t = 2.f * (float)(dx * dy) * (s2 * rh);
                    pu2 = 1.f + t; ps2 = 1.f - t;
                } else if (dx != 0) {                  // horizontal
                    pu2 = 0.5f + c2 * rh; ps2 = 0.5f - c2 * rh;
                } else {                               // vertical
                    pu2 = 0.5f - c2 * rh; ps2 = 0.5f + c2 * rh;
                }
                const float bp = 0.5f * (bc + bn);
                const float hp = 0.5f * (yc + yn);
                const float E = __expf(hp);
                const float iu = __fdividef(1.f, bp * E);   // 1/sigma_u
                const float is = E * E * iu;                // 1/sigma_s
                const float q = pu2 * (iu * iu) + ps2 * (is * is);
                cv = __expf(-q) * mun;
            }
            cmp[s] = cv;
            sum += cv;
        }
        const float inv = __fdividef(1.f, sum + 1e-6f);
        float* wrow = &wqlds[px * 52 + r * 12];
#pragma unroll
        for (int s = 0; s < 9; ++s) wrow[s] = cmp[s] * inv;
    }
    __syncthreads();

    // ---- stage B: lane = channel, wave w owns px w*8..w*8+7 ----
    const int w = tid >> 6, c = tid & 63;
    {
        const int hr0  = l0 >> 7;
        const int rows[3] = { max(hr0 - 1, 0) * Ww, hr0 * Ww, min(hr0 + 1, Hh - 1) * Ww };
        const int colbase = (l0 & (Ww - 1)) + w * 8;
        const float* vb = v + ((size_t)b * Ll) * 64 + c;

        float vv[3][10];
#pragma unroll
        for (int ry = 0; ry < 3; ++ry)
#pragma unroll
            for (int cx = 0; cx < 10; ++cx) {
                const int col = min(max(colbase + cx - 1, 0), Ww - 1);
                vv[ry][cx] = vb[(size_t)(rows[ry] + col) * 64];
            }

#pragma unroll
        for (int p = 0; p < 8; ++p) {
            const float* wrow = &wqlds[(w * 8 + p) * 52];
            float av[4];
#pragma unroll
            for (int r = 0; r < 4; ++r) {
                const float4 w0 = *(const float4*)(wrow + r * 12);      // s0..3
                const float4 w1 = *(const float4*)(wrow + r * 12 + 4);  // s4..7
                const float  w8 = wrow[r * 12 + 8];
                float a;
                a = w0.x * vv[0][p];
                a = fmaf(w0.y, vv[0][p + 1], a);
                a = fmaf(w0.z, vv[0][p + 2], a);
                a = fmaf(w0.w, vv[1][p],     a);
                a = fmaf(w1.x, vv[1][p + 1], a);
                a = fmaf(w1.y, vv[1][p + 2], a);
                a = fmaf(w1.z, vv[2][p],     a);
                a = fmaf(w1.w, vv[2][p + 1], a);
                a = fmaf(w8,   vv[2][p + 2], a);
                av[r] = a;
            }
            uint2 u;
            u.x = cvt_pk_bf16(av[0], av[1]);
            u.y = cvt_pk_bf16(av[2], av[3]);
            *((uint2*)(&agg[w * 8 + p][0]) + c) = u;    // m' = c*4+r
        }
    }

    // A fragments: issue before the barrier (in flight across it)
    const int ar    = tid & 15;
    const int chunk = (tid >> 4) & 3;
    const int o0    = w * 16;
    const unsigned short* aPtr = pwb16 + (o0 + ar) * 256 + chunk * 8;
    short8 af[8];
#pragma unroll
    for (int kt = 0; kt < 8; ++kt) af[kt] = *(const short8*)(aPtr + kt * 32);

    __syncthreads();

    // ---- stage C: MFMA pointwise, 2 p-tiles, A reused ----
    f32x4 d0, d1;
#pragma unroll
    for (int q = 0; q < 4; ++q) {
        const float bv = pw_b[o0 + chunk * 4 + q];
        d0[q] = bv; d1[q] = bv;
    }
    const unsigned short* b0 = &agg[ 0 + ar][chunk * 8];
    const unsigned short* b1 = &agg[16 + ar][chunk * 8];
#pragma unroll
    for (int kt = 0; kt < 8; ++kt) {
        d0 = __builtin_amdgcn_mfma_f32_16x16x32_bf16(af[kt], *(const short8*)(b0 + kt * 32), d0, 0, 0, 0);
        d1 = __builtin_amdgcn_mfma_f32_16x16x32_bf16(af[kt], *(const short8*)(b1 + kt * 32), d1, 0, 0, 0);
    }

#pragma unroll
    for (int q = 0; q < 4; ++q) {
        const int o = o0 + chunk * 4 + q;
        float* ob = out + ((size_t)b * Co + o) * Ll + l0 + ar;
        ob[0]  = d0[q];
        ob[16] = d1[q];
    }
}

// ---------------- launch ----------------
extern "C" void kernel_launch(void* const* d_in, const int* in_sizes, int n_in,
                              void* d_out, int out_size, void* d_ws, size_t ws_size,
                              hipStream_t stream)
{
    const float* x       = (const float*)d_in[0];
    const float* gate_w  = (const float*)d_in[1];
    const float* gate_b  = (const float*)d_in[2];
    const float* value_w = (const float*)d_in[3];
    const float* geom_w  = (const float*)d_in[4];
    const float* geom_b  = (const float*)d_in[5];
    const float* pw_w    = (const float*)d_in[6];
    const float* pw_b    = (const float*)d_in[7];
    float* out = (float*)d_out;

    float* ws  = (float*)d_ws;
    float* v    = ws;                                  // B*L*64   = 8388608
    float* mu   = v    + (size_t)Bx * Ll * 64;         // B*4*L    = 524288
    float* cs2  = mu   + (size_t)Bx * 4 * Ll;
    float* sn2  = cs2  + (size_t)Bx * 4 * Ll;
    float* bse  = sn2  + (size_t)Bx * 4 * Ll;
    float* hyp  = bse  + (size_t)Bx * 4 * Ll;
    float* wt16 = hyp  + (size_t)Bx * 4 * Ll;                 // 1024 f
    unsigned short* vwb16 = (unsigned short*)(wt16 + 1024);   // 4096 us
    unsigned short* pwb16 = vwb16 + 4096;                     // 16384 us
    // total ws: ~44 MB

    k0_pack_weights<<<8, 256, 0, stream>>>(gate_w, geom_w, value_w, pw_w,
                                           wt16, vwb16, pwb16);
    k1_project<<<NPIX / 64, 256, 0, stream>>>(x, vwb16, wt16, gate_b, geom_b,
                                              v, mu, cs2, sn2, bse, hyp);
    k23_fused<<<NPIX / TP, 256, 0, stream>>>(mu, cs2, sn2, bse, hyp,
                                             v, pwb16, pw_b, out);
}